// Round 1
// baseline (345.379 us; speedup 1.0000x reference)
//
#include <hip/hip_runtime.h>
#include <math.h>

#define E_    256
#define H_    512
#define F_    100
#define MCL_  500
#define CTX_  499
#define V_    128000
#define EPS_  1e-8f

// workspace layout (float offsets)
#define WS_FE      0                      // 500*256 fact embeddings (row 499 = mean fact)
#define WS_ENERGY  (WS_FE + MCL_*E_)      // 500
#define WS_EBIAS   (WS_ENERGY + MCL_)     // 500 (attn1_b + h0-part of attn1_W)
#define WS_AW      (WS_EBIAS + MCL_)      // 500
#define WS_AWF     (WS_AW + MCL_)         // 256 attn-weighted facts
#define WS_FMAX    (WS_AWF + E_)          // 256 emb of argmax fact
#define WS_GI      (WS_FMAX + E_)         // 1536
#define WS_GH      (WS_GI + 3*H_)         // 1536
#define WS_ACT     (WS_GH + 3*H_)         // 512 relu(out1)
#define WS_HNEW    (WS_ACT + H_)          // 512
#define WS_LOGITS  (WS_HNEW + H_)         // 128000
#define WS_BSUM    (WS_LOGITS + V_)       // 512 per-block sum-exp partials
#define WS_LOGZ    (WS_BSUM + 512)        // 1

__device__ __forceinline__ float wred(float v) {
#pragma unroll
  for (int o = 32; o; o >>= 1) v += __shfl_xor(v, o, 64);
  return v;
}

__device__ __forceinline__ float dot4(float4 a, float4 b) {
  return a.x*b.x + a.y*b.y + a.z*b.z + a.w*b.w;
}

// K1: facts[i,e] = sum_f word_emb[ctx[i,f],e] * l(f,e)
__global__ __launch_bounds__(256) void k_encode(const int* __restrict__ ctx,
                                                const float* __restrict__ wemb,
                                                float* __restrict__ fe) {
  __shared__ int toks[F_];
  const int i = blockIdx.x;
  const int e = threadIdx.x;
  if (e < F_) toks[e] = ctx[i * F_ + e];
  __syncthreads();
  const float en = e * (1.0f / 255.0f);
  float acc0 = 0.f, acc1 = 0.f;
#pragma unroll 2
  for (int f = 0; f < F_; f += 2) {
    float s0 = f * (1.0f / 99.0f);
    float s1 = (f + 1) * (1.0f / 99.0f);
    float l0 = (1.0f - s0) - en * (1.0f - 2.0f * s0);
    float l1 = (1.0f - s1) - en * (1.0f - 2.0f * s1);
    acc0 = fmaf(wemb[(size_t)toks[f]     * E_ + e], l0, acc0);
    acc1 = fmaf(wemb[(size_t)toks[f + 1] * E_ + e], l1, acc1);
  }
  fe[i * E_ + e] = acc0 + acc1;
}

// K2: mean of first nf fact rows -> row 499
__global__ __launch_bounds__(256) void k_mean(float* __restrict__ fe,
                                              const int* __restrict__ nfp) {
  const int e = threadIdx.x;
  const int nf = *nfp;
  float s = 0.f;
  for (int i = 0; i < nf; ++i) s += fe[i * E_ + e];
  fe[CTX_ * E_ + e] = s / (float)nf;
}

// K3: ebias[j] = attn1_b[j] + h0 . attn1_W[j, 256:768]
__global__ __launch_bounds__(256) void k_ebias(const float* __restrict__ a1W,
                                               const float* __restrict__ a1b,
                                               const float* __restrict__ h0,
                                               float* __restrict__ ebias) {
  const int lane = threadIdx.x & 63;
  const int wid = (blockIdx.x * blockDim.x + threadIdx.x) >> 6;
  const int nw = (gridDim.x * blockDim.x) >> 6;
  const float4* h4 = (const float4*)h0;
  float4 x = h4[lane], yv = h4[lane + 64];
  for (int j = wid; j < MCL_; j += nw) {
    const float4* w4 = (const float4*)(a1W + (size_t)j * (E_ + H_) + E_);
    float acc = dot4(w4[lane], x) + dot4(w4[lane + 64], yv);
    acc = wred(acc);
    if (lane == 0) ebias[j] = acc + a1b[j];
  }
}

// K4: energy[i] = a2b + sum_j a2W[j] * tanh(fe[i].A1[j,0:256] + ebias[j])
__global__ __launch_bounds__(256) void k_energy(const float* __restrict__ fe,
                                                const float* __restrict__ a1W,
                                                const float* __restrict__ ebias,
                                                const float* __restrict__ a2W,
                                                const float* __restrict__ a2b,
                                                float* __restrict__ energy) {
  __shared__ float sfe[4][E_];
  __shared__ float sred[4][256];
  const int t = threadIdx.x;
  const int i0 = blockIdx.x * 4;
#pragma unroll
  for (int r = 0; r < 4; ++r) sfe[r][t] = fe[(i0 + r) * E_ + t];
  __syncthreads();
  float c0 = 0.f, c1 = 0.f, c2 = 0.f, c3 = 0.f;
  const float4* s0 = (const float4*)sfe[0];
  const float4* s1 = (const float4*)sfe[1];
  const float4* s2 = (const float4*)sfe[2];
  const float4* s3 = (const float4*)sfe[3];
  for (int j = t; j < MCL_; j += 256) {
    const float4* w4 = (const float4*)(a1W + (size_t)j * (E_ + H_));
    float d0 = 0.f, d1 = 0.f, d2 = 0.f, d3 = 0.f;
#pragma unroll 8
    for (int q = 0; q < E_ / 4; ++q) {
      float4 a = w4[q];
      d0 += dot4(a, s0[q]);
      d1 += dot4(a, s1[q]);
      d2 += dot4(a, s2[q]);
      d3 += dot4(a, s3[q]);
    }
    float bj = ebias[j], wj = a2W[j];
    c0 = fmaf(wj, tanhf(d0 + bj), c0);
    c1 = fmaf(wj, tanhf(d1 + bj), c1);
    c2 = fmaf(wj, tanhf(d2 + bj), c2);
    c3 = fmaf(wj, tanhf(d3 + bj), c3);
  }
  sred[0][t] = c0; sred[1][t] = c1; sred[2][t] = c2; sred[3][t] = c3;
  __syncthreads();
  for (int s = 128; s; s >>= 1) {
    if (t < s) {
#pragma unroll
      for (int r = 0; r < 4; ++r) sred[r][t] += sred[r][t + s];
    }
    __syncthreads();
  }
  if (t < 4) energy[i0 + t] = sred[t][0] + a2b[0];
}

// K5: softmax+mask+renorm+log_aw+argmax, awf = aw @ fe, gather argmax row
__global__ __launch_bounds__(512) void k_softmax(const float* __restrict__ energy,
                                                 const float* __restrict__ fe,
                                                 const int* __restrict__ nfp,
                                                 float* __restrict__ aw_ws,
                                                 float* __restrict__ awf,
                                                 float* __restrict__ fmaxrow,
                                                 float* __restrict__ out_logaw) {
  __shared__ float sred[512];
  __shared__ int   sidx[512];
  __shared__ float saw[512];
  const int t = threadIdx.x;
  const int nf = *nfp;

  float ev = (t < MCL_) ? energy[t] : -1e30f;
  sred[t] = ev; __syncthreads();
  for (int s = 256; s; s >>= 1) { if (t < s) sred[t] = fmaxf(sred[t], sred[t + s]); __syncthreads(); }
  float mx = sred[0]; __syncthreads();

  float p = (t < MCL_) ? __expf(ev - mx) : 0.f;
  sred[t] = p; __syncthreads();
  for (int s = 256; s; s >>= 1) { if (t < s) sred[t] += sred[t + s]; __syncthreads(); }
  float S1 = sred[0]; __syncthreads();

  float m = ((t < nf) || (t == MCL_ - 1)) ? 1.f : 0.f;
  float awv = (t < MCL_) ? (p / S1 * m + EPS_) : 0.f;
  sred[t] = awv; __syncthreads();
  for (int s = 256; s; s >>= 1) { if (t < s) sred[t] += sred[t + s]; __syncthreads(); }
  float S2 = sred[0]; __syncthreads();

  float aw = awv / S2;
  if (t < MCL_) { aw_ws[t] = aw; out_logaw[t] = logf(aw); }
  saw[t] = (t < MCL_) ? aw : -1.f;
  sred[t] = saw[t]; sidx[t] = t; __syncthreads();
  for (int s = 256; s; s >>= 1) {
    if (t < s) {
      float o = sred[t + s]; int oi = sidx[t + s];
      if (o > sred[t] || (o == sred[t] && oi < sidx[t])) { sred[t] = o; sidx[t] = oi; }
    }
    __syncthreads();
  }
  const int fidx = sidx[0];
  __syncthreads();

  // awf[e] = sum_i aw[i]*fe[i,e]; split i-range across two halves of the block
  const int e = t & 255, half = t >> 8;
  float part = 0.f;
  const int ib = half * 250;
#pragma unroll 4
  for (int i = ib; i < ib + 250; ++i) part = fmaf(saw[i], fe[i * E_ + e], part);
  sred[t] = part; __syncthreads();
  if (half == 0) {
    awf[e] = sred[e] + sred[e + 256];
    fmaxrow[e] = fe[fidx * E_ + e];
  }
}

// K6: gi = x.W_ih^T + b_ih (cols 256..355 are zero-input), gh = h0.W_hh^T + b_hh
__global__ __launch_bounds__(256) void k_gates(const float* __restrict__ Wih,
                                               const float* __restrict__ bih,
                                               const float* __restrict__ Whh,
                                               const float* __restrict__ bhh,
                                               const float* __restrict__ wemb,
                                               const float* __restrict__ fmaxrow,
                                               const float* __restrict__ h0,
                                               float* __restrict__ gi,
                                               float* __restrict__ gh) {
  const int lane = threadIdx.x & 63;
  const int gw = (blockIdx.x * blockDim.x + threadIdx.x) >> 6;
  const int nw = (gridDim.x * blockDim.x) >> 6;
  const float4* xa = (const float4*)(wemb + E_);  // word_emb row 1
  const float4* xb = (const float4*)fmaxrow;
  const float4* h4 = (const float4*)h0;
  float4 xav = xa[lane], xbv = xb[lane];
  float4 hx = h4[lane], hy = h4[lane + 64];
  for (int task = gw; task < 2 * 3 * H_; task += nw) {
    if (task < 3 * H_) {
      const int k = task;
      const float* w = Wih + (size_t)k * (2 * E_ + F_);
      float acc = dot4(((const float4*)w)[lane], xav)
                + dot4(((const float4*)(w + E_ + F_))[lane], xbv);
      acc = wred(acc);
      if (lane == 0) gi[k] = acc + bih[k];
    } else {
      const int k = task - 3 * H_;
      const float4* w4 = (const float4*)(Whh + (size_t)k * H_);
      float acc = dot4(w4[lane], hx) + dot4(w4[lane + 64], hy);
      acc = wred(acc);
      if (lane == 0) gh[k] = acc + bhh[k];
    }
  }
}

// K7: GRU cell combine
__global__ __launch_bounds__(512) void k_gru(const float* __restrict__ gi,
                                             const float* __restrict__ gh,
                                             const float* __restrict__ h0,
                                             float* __restrict__ hnew,
                                             float* __restrict__ out_hidden) {
  const int h = threadIdx.x;
  float r = 1.f / (1.f + __expf(-(gi[h] + gh[h])));
  float z = 1.f / (1.f + __expf(-(gi[H_ + h] + gh[H_ + h])));
  float n = tanhf(gi[2 * H_ + h] + r * gh[2 * H_ + h]);
  float hv = (1.f - z) * n + z * h0[h];
  hnew[h] = hv;
  out_hidden[h] = hv;
}

// K8: act = relu([h_new|awf] . out1_W^T + out1_b)
__global__ __launch_bounds__(256) void k_out1(const float* __restrict__ o1W,
                                              const float* __restrict__ o1b,
                                              const float* __restrict__ hnew,
                                              const float* __restrict__ awf,
                                              float* __restrict__ act) {
  __shared__ float cat[E_ + H_];
  const int t = threadIdx.x;
  for (int idx = t; idx < E_ + H_; idx += 256)
    cat[idx] = (idx < H_) ? hnew[idx] : awf[idx - H_];
  __syncthreads();
  const int lane = t & 63;
  const int wid = blockIdx.x * 4 + (t >> 6);
  const float4* c4 = (const float4*)cat;
  for (int h = wid; h < H_; h += gridDim.x * 4) {
    const float4* w4 = (const float4*)(o1W + (size_t)h * (E_ + H_));
    float acc = 0.f;
#pragma unroll
    for (int q = 0; q < 3; ++q) acc += dot4(w4[lane + 64 * q], c4[lane + 64 * q]);
    acc = wred(acc);
    if (lane == 0) act[h] = fmaxf(acc + o1b[h], 0.f);
  }
}

// K9: logits[v] = act . out2_W[v] + out2_b[v]; per-block partial sum of exp(logit)
__global__ __launch_bounds__(256) void k_vocab(const float* __restrict__ o2W,
                                               const float* __restrict__ o2b,
                                               const float* __restrict__ act,
                                               float* __restrict__ logits,
                                               float* __restrict__ bsum) {
  __shared__ float4 sact[128];
  __shared__ float swsum[4];
  const int t = threadIdx.x;
  if (t < 128) sact[t] = ((const float4*)act)[t];
  __syncthreads();
  const int lane = t & 63, w = t >> 6;
  const int gw = blockIdx.x * 4 + w;
  const int nwaves = gridDim.x * 4;
  float4 x = sact[lane], yv = sact[lane + 64];
  float sumexp = 0.f;
  for (int v = gw; v < V_; v += nwaves) {
    const float4* w4 = (const float4*)(o2W + (size_t)v * H_);
    float acc = dot4(w4[lane], x) + dot4(w4[lane + 64], yv);
    acc = wred(acc);
    if (lane == 0) {
      float lg = acc + o2b[v];
      logits[v] = lg;
      sumexp += __expf(lg);
    }
  }
  if (lane == 0) swsum[w] = sumexp;
  __syncthreads();
  if (t == 0) bsum[blockIdx.x] = swsum[0] + swsum[1] + swsum[2] + swsum[3];
}

// K10: logZ = log(sum of partials)   (logits are tiny -> no max-shift needed)
__global__ __launch_bounds__(512) void k_logz(const float* __restrict__ bsum,
                                              float* __restrict__ logz) {
  __shared__ float sred[512];
  const int t = threadIdx.x;
  sred[t] = bsum[t];
  __syncthreads();
  for (int s = 256; s; s >>= 1) { if (t < s) sred[t] += sred[t + s]; __syncthreads(); }
  if (t == 0) *logz = logf(sred[0]);
}

// K11: y = logits - logZ
__global__ __launch_bounds__(256) void k_writey(const float* __restrict__ logits,
                                                const float* __restrict__ logz,
                                                float* __restrict__ y) {
  const int i = blockIdx.x * blockDim.x + threadIdx.x;
  const float lz = *logz;
  float4 l4 = ((const float4*)logits)[i];
  ((float4*)y)[i] = make_float4(l4.x - lz, l4.y - lz, l4.z - lz, l4.w - lz);
}

extern "C" void kernel_launch(void* const* d_in, const int* in_sizes, int n_in,
                              void* d_out, int out_size, void* d_ws, size_t ws_size,
                              hipStream_t stream) {
  const int*   ctx  = (const int*)d_in[0];
  const float* wemb = (const float*)d_in[1];
  const float* a1W  = (const float*)d_in[2];
  const float* a1b  = (const float*)d_in[3];
  const float* a2W  = (const float*)d_in[4];
  const float* a2b  = (const float*)d_in[5];
  const float* Wih  = (const float*)d_in[6];
  const float* Whh  = (const float*)d_in[7];
  const float* bih  = (const float*)d_in[8];
  const float* bhh  = (const float*)d_in[9];
  const float* o1W  = (const float*)d_in[10];
  const float* o1b  = (const float*)d_in[11];
  const float* o2W  = (const float*)d_in[12];
  const float* o2b  = (const float*)d_in[13];
  const float* h0   = (const float*)d_in[14];
  const int*   nfp  = (const int*)d_in[15];
  float* ws = (float*)d_ws;
  float* y  = (float*)d_out;

  k_encode<<<CTX_, 256, 0, stream>>>(ctx, wemb, ws + WS_FE);
  k_mean  <<<1, 256, 0, stream>>>(ws + WS_FE, nfp);
  k_ebias <<<4, 256, 0, stream>>>(a1W, a1b, h0, ws + WS_EBIAS);
  k_energy<<<MCL_ / 4, 256, 0, stream>>>(ws + WS_FE, a1W, ws + WS_EBIAS, a2W, a2b,
                                         ws + WS_ENERGY);
  k_softmax<<<1, 512, 0, stream>>>(ws + WS_ENERGY, ws + WS_FE, nfp, ws + WS_AW,
                                   ws + WS_AWF, ws + WS_FMAX, y + V_);
  k_gates<<<16, 256, 0, stream>>>(Wih, bih, Whh, bhh, wemb, ws + WS_FMAX, h0,
                                  ws + WS_GI, ws + WS_GH);
  k_gru  <<<1, H_, 0, stream>>>(ws + WS_GI, ws + WS_GH, h0, ws + WS_HNEW, y + V_ + MCL_);
  k_out1 <<<8, 256, 0, stream>>>(o1W, o1b, ws + WS_HNEW, ws + WS_AWF, ws + WS_ACT);
  k_vocab<<<512, 256, 0, stream>>>(o2W, o2b, ws + WS_ACT, ws + WS_LOGITS, ws + WS_BSUM);
  k_logz <<<1, 512, 0, stream>>>(ws + WS_BSUM, ws + WS_LOGZ);
  k_writey<<<V_ / 1024, 256, 0, stream>>>(ws + WS_LOGITS, ws + WS_LOGZ, y);
}

// Round 3
// 141.938 us; speedup vs baseline: 2.4333x; 2.4333x over previous
//
#include <hip/hip_runtime.h>
#include <math.h>

#define E_    256
#define H_    512
#define F_    100
#define MCL_  500
#define CTX_  499
#define V_    128000
#define EPS_  1e-8f

typedef float f4v __attribute__((ext_vector_type(4)));

// workspace layout (float offsets)
#define WS_FE      0                      // 500*256 fact embeddings (row 499 = mean fact)
#define WS_ENERGY  (WS_FE + MCL_*E_)      // 500
#define WS_EBIAS   (WS_ENERGY + MCL_)     // 500
#define WS_AWF     (WS_EBIAS + MCL_)      // 256 attn-weighted facts
#define WS_FMAX    (WS_AWF + E_)          // 256 emb of argmax fact
#define WS_GI      (WS_FMAX + E_)         // 1536
#define WS_GH      (WS_GI + 3*H_)         // 1536
#define WS_ACT     (WS_GH + 3*H_)         // 512 relu(out1)
#define WS_LOGITS  (WS_ACT + H_)          // 128000
#define WS_BSUM    (WS_LOGITS + V_)       // 1024 per-block sum-exp partials

__device__ __forceinline__ float wred64(float v) {
#pragma unroll
  for (int o = 32; o; o >>= 1) v += __shfl_xor(v, o, 64);
  return v;
}
__device__ __forceinline__ float qred16(float v) {
#pragma unroll
  for (int o = 8; o; o >>= 1) v += __shfl_xor(v, o, 64);
  return v;
}
__device__ __forceinline__ float dot4(float4 a, float4 b) {
  return a.x*b.x + a.y*b.y + a.z*b.z + a.w*b.w;
}
__device__ __forceinline__ float dot4v(f4v a, f4v b) {
  return a.x*b.x + a.y*b.y + a.z*b.z + a.w*b.w;
}

// K1: facts[i,e] = sum_f word_emb[ctx[i,f],e] * l(f,e)   (deep ILP gather)
__global__ __launch_bounds__(256) void k_encode(const int* __restrict__ ctx,
                                                const float* __restrict__ wemb,
                                                float* __restrict__ fe) {
  __shared__ int toks[F_];
  const int i = blockIdx.x;
  const int e = threadIdx.x;
  if (e < F_) toks[e] = ctx[i * F_ + e];
  __syncthreads();
  const float en = e * (1.0f / 255.0f);
  float a0 = 0.f, a1 = 0.f, a2 = 0.f, a3 = 0.f;
#pragma unroll 5
  for (int f = 0; f < F_; f += 4) {
#pragma unroll
    for (int u = 0; u < 4; ++u) {
      float s = (f + u) * (1.0f / 99.0f);
      float l = (1.0f - s) - en * (1.0f - 2.0f * s);
      float v = wemb[(size_t)toks[f + u] * E_ + e];
      if (u == 0) a0 = fmaf(v, l, a0);
      else if (u == 1) a1 = fmaf(v, l, a1);
      else if (u == 2) a2 = fmaf(v, l, a2);
      else a3 = fmaf(v, l, a3);
    }
  }
  fe[i * E_ + e] = (a0 + a1) + (a2 + a3);
}

// K2: block 0 -> mean fact row; blocks 1.. -> ebias[j] = a1b[j] + h0 . a1W[j,256:768]
__global__ __launch_bounds__(256) void k_prep(float* __restrict__ fe,
                                              const int* __restrict__ nfp,
                                              const float* __restrict__ a1W,
                                              const float* __restrict__ a1b,
                                              const float* __restrict__ h0,
                                              float* __restrict__ ebias) {
  const int t = threadIdx.x;
  if (blockIdx.x == 0) {
    const int nf = *nfp;
    float s0 = 0.f, s1 = 0.f, s2 = 0.f, s3 = 0.f;
    int i = 0;
    for (; i + 4 <= nf; i += 4) {
      s0 += fe[(i + 0) * E_ + t]; s1 += fe[(i + 1) * E_ + t];
      s2 += fe[(i + 2) * E_ + t]; s3 += fe[(i + 3) * E_ + t];
    }
    for (; i < nf; ++i) s0 += fe[i * E_ + t];
    fe[CTX_ * E_ + t] = ((s0 + s1) + (s2 + s3)) / (float)nf;
    return;
  }
  const int lane = t & 63, sub = lane & 15, grp = lane >> 4;
  const int wid = (blockIdx.x - 1) * 4 + (t >> 6);
  const int nW = (gridDim.x - 1) * 4;
  const float4* h4 = (const float4*)h0;
  float4 hr[8];
#pragma unroll
  for (int q = 0; q < 8; ++q) hr[q] = h4[sub + q * 16];
  for (int j0 = wid * 4; j0 < MCL_; j0 += nW * 4) {
    const int j = j0 + grp;
    if (j < MCL_) {
      const float4* w4 = (const float4*)(a1W + (size_t)j * (E_ + H_) + E_);
      float acc = 0.f;
#pragma unroll
      for (int q = 0; q < 8; ++q) acc += dot4(w4[sub + q * 16], hr[q]);
      acc = qred16(acc);
      if (sub == 0) ebias[j] = acc + a1b[j];
    }
  }
}

// K3: energy[i] = a2b + sum_j a2W[j] * tanh(fe[i].A1[j,0:256] + ebias[j])
__global__ __launch_bounds__(256) void k_energy(const float* __restrict__ fe,
                                                const float* __restrict__ a1W,
                                                const float* __restrict__ ebias,
                                                const float* __restrict__ a2W,
                                                const float* __restrict__ a2b,
                                                float* __restrict__ energy) {
  __shared__ float sfe[4][E_];
  __shared__ float sred[4][256];
  const int t = threadIdx.x;
  const int i0 = blockIdx.x * 4;
#pragma unroll
  for (int r = 0; r < 4; ++r) sfe[r][t] = fe[(i0 + r) * E_ + t];
  __syncthreads();
  float c0 = 0.f, c1 = 0.f, c2 = 0.f, c3 = 0.f;
  const float4* s0 = (const float4*)sfe[0];
  const float4* s1 = (const float4*)sfe[1];
  const float4* s2 = (const float4*)sfe[2];
  const float4* s3 = (const float4*)sfe[3];
  for (int j = t; j < MCL_; j += 256) {
    const float4* w4 = (const float4*)(a1W + (size_t)j * (E_ + H_));
    float d0 = 0.f, d1 = 0.f, d2 = 0.f, d3 = 0.f;
#pragma unroll 8
    for (int q = 0; q < E_ / 4; ++q) {
      float4 a = w4[q];
      d0 += dot4(a, s0[q]);
      d1 += dot4(a, s1[q]);
      d2 += dot4(a, s2[q]);
      d3 += dot4(a, s3[q]);
    }
    float bj = ebias[j], wj = a2W[j];
    c0 = fmaf(wj, tanhf(d0 + bj), c0);
    c1 = fmaf(wj, tanhf(d1 + bj), c1);
    c2 = fmaf(wj, tanhf(d2 + bj), c2);
    c3 = fmaf(wj, tanhf(d3 + bj), c3);
  }
  sred[0][t] = c0; sred[1][t] = c1; sred[2][t] = c2; sred[3][t] = c3;
  __syncthreads();
  for (int s = 128; s; s >>= 1) {
    if (t < s) {
#pragma unroll
      for (int r = 0; r < 4; ++r) sred[r][t] += sred[r][t + s];
    }
    __syncthreads();
  }
  if (t < 4) energy[i0 + t] = sred[t][0] + a2b[0];
}

// K4: softmax+mask+renorm+log_aw+argmax, awf = aw @ fe, gather argmax row
__global__ __launch_bounds__(512) void k_softmax(const float* __restrict__ energy,
                                                 const float* __restrict__ fe,
                                                 const int* __restrict__ nfp,
                                                 float* __restrict__ awf,
                                                 float* __restrict__ fmaxrow,
                                                 float* __restrict__ out_logaw) {
  __shared__ float sred[512];
  __shared__ int   sidx[512];
  __shared__ float saw[512];
  const int t = threadIdx.x;
  const int nf = *nfp;

  float ev = (t < MCL_) ? energy[t] : -1e30f;
  sred[t] = ev; __syncthreads();
  for (int s = 256; s; s >>= 1) { if (t < s) sred[t] = fmaxf(sred[t], sred[t + s]); __syncthreads(); }
  float mx = sred[0]; __syncthreads();

  float p = (t < MCL_) ? __expf(ev - mx) : 0.f;
  sred[t] = p; __syncthreads();
  for (int s = 256; s; s >>= 1) { if (t < s) sred[t] += sred[t + s]; __syncthreads(); }
  float S1 = sred[0]; __syncthreads();

  float m = ((t < nf) || (t == MCL_ - 1)) ? 1.f : 0.f;
  float awv = (t < MCL_) ? (p / S1 * m + EPS_) : 0.f;
  sred[t] = awv; __syncthreads();
  for (int s = 256; s; s >>= 1) { if (t < s) sred[t] += sred[t + s]; __syncthreads(); }
  float S2 = sred[0]; __syncthreads();

  float aw = awv / S2;
  if (t < MCL_) out_logaw[t] = logf(aw);
  saw[t] = (t < MCL_) ? aw : -1.f;
  sred[t] = saw[t]; sidx[t] = t; __syncthreads();
  for (int s = 256; s; s >>= 1) {
    if (t < s) {
      float o = sred[t + s]; int oi = sidx[t + s];
      if (o > sred[t] || (o == sred[t] && oi < sidx[t])) { sred[t] = o; sidx[t] = oi; }
    }
    __syncthreads();
  }
  const int fidx = sidx[0];
  __syncthreads();

  const int e = t & 255, half = t >> 8;
  float part = 0.f;
  const int ib = half * 250;
#pragma unroll 4
  for (int i = ib; i < ib + 250; ++i) part = fmaf(saw[i], fe[i * E_ + e], part);
  sred[t] = part; __syncthreads();
  if (half == 0) {
    awf[e] = sred[e] + sred[e + 256];
    fmaxrow[e] = fe[fidx * E_ + e];
  }
}

// K5: gi = x.W_ih^T + b_ih (zero dec_pos cols skipped), gh = h0.W_hh^T + b_hh
__global__ __launch_bounds__(256) void k_gates(const float* __restrict__ Wih,
                                               const float* __restrict__ bih,
                                               const float* __restrict__ Whh,
                                               const float* __restrict__ bhh,
                                               const float* __restrict__ wemb,
                                               const float* __restrict__ fmaxrow,
                                               const float* __restrict__ h0,
                                               float* __restrict__ gi,
                                               float* __restrict__ gh) {
  const int t = threadIdx.x;
  const int lane = t & 63, sub = lane & 15, grp = lane >> 4;
  const int gw = blockIdx.x * 4 + (t >> 6);
  const int nW = gridDim.x * 4;
  const float4* xa = (const float4*)(wemb + E_);  // word_emb row 1
  const float4* xb = (const float4*)fmaxrow;
  const float4* h4 = (const float4*)h0;
  float4 xar[4], xbr[4], hr[8];
#pragma unroll
  for (int q = 0; q < 4; ++q) { xar[q] = xa[sub + q * 16]; xbr[q] = xb[sub + q * 16]; }
#pragma unroll
  for (int q = 0; q < 8; ++q) hr[q] = h4[sub + q * 16];
  for (int r0 = gw * 4; r0 < 2 * 3 * H_; r0 += nW * 4) {
    const int r = r0 + grp;
    if (r < 3 * H_) {
      const float* wr = Wih + (size_t)r * (2 * E_ + F_);
      const float4* wA = (const float4*)wr;
      const float4* wB = (const float4*)(wr + E_ + F_);
      float acc = 0.f;
#pragma unroll
      for (int q = 0; q < 4; ++q)
        acc += dot4(wA[sub + q * 16], xar[q]) + dot4(wB[sub + q * 16], xbr[q]);
      acc = qred16(acc);
      if (sub == 0) gi[r] = acc + bih[r];
    } else {
      const int rr = r - 3 * H_;
      const float4* w4 = (const float4*)(Whh + (size_t)rr * H_);
      float acc = 0.f;
#pragma unroll
      for (int q = 0; q < 8; ++q) acc += dot4(w4[sub + q * 16], hr[q]);
      acc = qred16(acc);
      if (sub == 0) gh[rr] = acc + bhh[rr];
    }
  }
}

// K6: GRU combine (redundant per block) + act = relu([h_new|awf].out1_W^T + out1_b)
__global__ __launch_bounds__(256) void k_out1(const float* __restrict__ o1W,
                                              const float* __restrict__ o1b,
                                              const float* __restrict__ gi,
                                              const float* __restrict__ gh,
                                              const float* __restrict__ h0,
                                              const float* __restrict__ awf,
                                              float* __restrict__ act,
                                              float* __restrict__ out_hidden) {
  __shared__ float cat[H_ + E_];
  const int t = threadIdx.x;
#pragma unroll
  for (int h = t; h < H_; h += 256) {
    float r = 1.f / (1.f + __expf(-(gi[h] + gh[h])));
    float z = 1.f / (1.f + __expf(-(gi[H_ + h] + gh[H_ + h])));
    float n = tanhf(gi[2 * H_ + h] + r * gh[2 * H_ + h]);
    float hv = (1.f - z) * n + z * h0[h];
    cat[h] = hv;
    if (blockIdx.x == 0) out_hidden[h] = hv;
  }
  cat[H_ + t] = awf[t];
  __syncthreads();
  const int lane = t & 63, sub = lane & 15, grp = lane >> 4;
  const int gw = blockIdx.x * 4 + (t >> 6);
  const int nW = gridDim.x * 4;
  const float4* c4 = (const float4*)cat;
  for (int r0 = gw * 4; r0 < H_; r0 += nW * 4) {
    const int r = r0 + grp;
    const float4* w4 = (const float4*)(o1W + (size_t)r * (H_ + E_));
    float acc = 0.f;
#pragma unroll
    for (int q = 0; q < 12; ++q) acc += dot4(w4[sub + q * 16], c4[sub + q * 16]);
    acc = qred16(acc);
    if (sub == 0) act[r] = fmaxf(acc + o1b[r], 0.f);
  }
}

// K7: quarter-wave vocab GEMV + per-block sum-exp partials
__global__ __launch_bounds__(256) void k_vocab(const float* __restrict__ o2W,
                                               const float* __restrict__ o2b,
                                               const float* __restrict__ act,
                                               float* __restrict__ logits,
                                               float* __restrict__ bsum) {
  __shared__ float swsum[4];
  const int t = threadIdx.x;
  const int lane = t & 63, sub = lane & 15, grp = lane >> 4, w = t >> 6;
  const int gw = blockIdx.x * 4 + w;
  const int nW = gridDim.x * 4;
  const f4v* a4 = (const f4v*)act;
  f4v ar[8];
#pragma unroll
  for (int q = 0; q < 8; ++q) ar[q] = a4[sub + q * 16];
  float sumexp = 0.f;
  for (int v0 = gw * 4; v0 < V_; v0 += nW * 4) {
    const int v = v0 + grp;
    const f4v* w4 = (const f4v*)(o2W + (size_t)v * H_);
    float acc = 0.f;
#pragma unroll
    for (int q = 0; q < 8; ++q) {
      f4v wv = __builtin_nontemporal_load(&w4[sub + q * 16]);
      acc += dot4v(wv, ar[q]);
    }
    acc = qred16(acc);
    if (sub == 0) {
      float lg = acc + o2b[v];
      logits[v] = lg;
      sumexp += __expf(lg);
    }
  }
  sumexp = wred64(sumexp);
  if (lane == 0) swsum[w] = sumexp;
  __syncthreads();
  if (t == 0) bsum[blockIdx.x] = swsum[0] + swsum[1] + swsum[2] + swsum[3];
}

// K8: redundant logZ reduce per block + y = logits - logZ
__global__ __launch_bounds__(256) void k_final(const float* __restrict__ logits,
                                               const float* __restrict__ bsum,
                                               float* __restrict__ y) {
  __shared__ float sr[256];
  const int t = threadIdx.x;
  float s = bsum[t] + bsum[t + 256] + bsum[t + 512] + bsum[t + 768];
  sr[t] = s; __syncthreads();
  for (int o = 128; o; o >>= 1) { if (t < o) sr[t] += sr[t + o]; __syncthreads(); }
  const float lz = logf(sr[0]);
  const int i = blockIdx.x * 256 + t;
  float4 l = ((const float4*)logits)[i];
  ((float4*)y)[i] = make_float4(l.x - lz, l.y - lz, l.z - lz, l.w - lz);
}

extern "C" void kernel_launch(void* const* d_in, const int* in_sizes, int n_in,
                              void* d_out, int out_size, void* d_ws, size_t ws_size,
                              hipStream_t stream) {
  const int*   ctx  = (const int*)d_in[0];
  const float* wemb = (const float*)d_in[1];
  const float* a1W  = (const float*)d_in[2];
  const float* a1b  = (const float*)d_in[3];
  const float* a2W  = (const float*)d_in[4];
  const float* a2b  = (const float*)d_in[5];
  const float* Wih  = (const float*)d_in[6];
  const float* Whh  = (const float*)d_in[7];
  const float* bih  = (const float*)d_in[8];
  const float* bhh  = (const float*)d_in[9];
  const float* o1W  = (const float*)d_in[10];
  const float* o1b  = (const float*)d_in[11];
  const float* o2W  = (const float*)d_in[12];
  const float* o2b  = (const float*)d_in[13];
  const float* h0   = (const float*)d_in[14];
  const int*   nfp  = (const int*)d_in[15];
  float* ws = (float*)d_ws;
  float* y  = (float*)d_out;

  k_encode<<<CTX_, 256, 0, stream>>>(ctx, wemb, ws + WS_FE);
  k_prep  <<<9, 256, 0, stream>>>(ws + WS_FE, nfp, a1W, a1b, h0, ws + WS_EBIAS);
  k_energy<<<MCL_ / 4, 256, 0, stream>>>(ws + WS_FE, a1W, ws + WS_EBIAS, a2W, a2b,
                                         ws + WS_ENERGY);
  k_softmax<<<1, 512, 0, stream>>>(ws + WS_ENERGY, ws + WS_FE, nfp,
                                   ws + WS_AWF, ws + WS_FMAX, y + V_);
  k_gates<<<64, 256, 0, stream>>>(Wih, bih, Whh, bhh, wemb, ws + WS_FMAX, h0,
                                  ws + WS_GI, ws + WS_GH);
  k_out1 <<<32, 256, 0, stream>>>(o1W, o1b, ws + WS_GI, ws + WS_GH, h0,
                                  ws + WS_AWF, ws + WS_ACT, y + V_ + MCL_);
  k_vocab<<<1024, 256, 0, stream>>>(o2W, o2b, ws + WS_ACT, ws + WS_LOGITS, ws + WS_BSUM);
  k_final<<<V_ / 1024, 256, 0, stream>>>(ws + WS_LOGITS, ws + WS_BSUM, y);
}

// Round 4
// 127.445 us; speedup vs baseline: 2.7100x; 1.1137x over previous
//
#include <hip/hip_runtime.h>
#include <math.h>

#define E_    256
#define H_    512
#define F_    100
#define MCL_  500
#define CTX_  499
#define V_    128000
#define EPS_  1e-8f

typedef float f4v __attribute__((ext_vector_type(4)));

// workspace layout (float offsets)
#define WS_FE      0                      // 500*256 (row 499 = mean fact)
#define WS_ENERGY  (WS_FE + MCL_*E_)      // 500
#define WS_EBIAS   (WS_ENERGY + MCL_)     // 500
#define WS_AWF     (WS_EBIAS + MCL_)      // 256
#define WS_FMAX    (WS_AWF + E_)          // 256
#define WS_HNEW    (WS_FMAX + E_)         // 512
#define WS_ACT     (WS_HNEW + H_)         // 512
#define WS_LOGITS  (WS_ACT + H_)          // 128000
#define WS_BSUM    (WS_LOGITS + V_)       // 1024
#define WS_CNT     (WS_BSUM + 1024)       // 1 int

__device__ __forceinline__ float wred64(float v) {
#pragma unroll
  for (int o = 32; o; o >>= 1) v += __shfl_xor(v, o, 64);
  return v;
}
__device__ __forceinline__ float qred16(float v) {
#pragma unroll
  for (int o = 8; o; o >>= 1) v += __shfl_xor(v, o, 64);
  return v;
}
__device__ __forceinline__ float dot4(float4 a, float4 b) {
  return a.x*b.x + a.y*b.y + a.z*b.z + a.w*b.w;
}
__device__ __forceinline__ float dot4v(f4v a, f4v b) {
  return a.x*b.x + a.y*b.y + a.z*b.z + a.w*b.w;
}

// K1: blocks 0-249: facts (2 rows/block, float2); blocks 250-257: ebias; b0 zeroes cnt
__global__ __launch_bounds__(256) void k_encode(const int* __restrict__ ctx,
                                                const float* __restrict__ wemb,
                                                float* __restrict__ fe,
                                                const float* __restrict__ a1W,
                                                const float* __restrict__ a1b,
                                                const float* __restrict__ h0,
                                                float* __restrict__ ebias,
                                                int* __restrict__ cnt) {
  __shared__ int toks[2][F_];
  const int t = threadIdx.x;
  if (blockIdx.x >= 250) {  // ebias: ebias[j] = a1b[j] + h0 . a1W[j,256:768]
    const int lane = t & 63, sub = lane & 15, grp = lane >> 4;
    const int wid = (blockIdx.x - 250) * 4 + (t >> 6);
    const float4* h4 = (const float4*)h0;
    float4 hr[8];
#pragma unroll
    for (int q = 0; q < 8; ++q) hr[q] = h4[sub + q * 16];
    for (int j0 = wid * 4; j0 < MCL_; j0 += 32 * 4) {
      const int j = j0 + grp;
      if (j < MCL_) {
        const float4* w4 = (const float4*)(a1W + (size_t)j * (E_ + H_) + E_);
        float acc = 0.f;
#pragma unroll
        for (int q = 0; q < 8; ++q) acc += dot4(w4[sub + q * 16], hr[q]);
        acc = qred16(acc);
        if (sub == 0) ebias[j] = acc + a1b[j];
      }
    }
    return;
  }
  if (blockIdx.x == 0 && t == 0) *cnt = 0;
  const int i0 = blockIdx.x * 2;
  const int i1 = i0 + 1;
  if (t < F_) toks[0][t] = ctx[i0 * F_ + t];
  else if (t < 2 * F_) toks[1][t - F_] = (i1 < CTX_) ? ctx[i1 * F_ + (t - F_)] : 0;
  __syncthreads();
  const int row = t >> 7, tt = t & 127;
  const int i = i0 + row;
  const float e0n = (2 * tt) * (1.0f / 255.0f);
  const float e1n = (2 * tt + 1) * (1.0f / 255.0f);
  float x0 = 0.f, y0 = 0.f, x1 = 0.f, y1 = 0.f, x2 = 0.f, y2 = 0.f, x3 = 0.f, y3 = 0.f;
#pragma unroll 5
  for (int f = 0; f < F_; f += 4) {
#pragma unroll
    for (int u = 0; u < 4; ++u) {
      float s = (f + u) * (1.0f / 99.0f);
      float A = 1.0f - s, B = 1.0f - 2.0f * s;
      float l0 = A - e0n * B, l1 = A - e1n * B;
      float2 v = ((const float2*)(wemb + (size_t)toks[row][f + u] * E_))[tt];
      if (u == 0)      { x0 = fmaf(v.x, l0, x0); y0 = fmaf(v.y, l1, y0); }
      else if (u == 1) { x1 = fmaf(v.x, l0, x1); y1 = fmaf(v.y, l1, y1); }
      else if (u == 2) { x2 = fmaf(v.x, l0, x2); y2 = fmaf(v.y, l1, y2); }
      else             { x3 = fmaf(v.x, l0, x3); y3 = fmaf(v.y, l1, y3); }
    }
  }
  if (i < CTX_) {
    float2 r; r.x = (x0 + x1) + (x2 + x3); r.y = (y0 + y1) + (y2 + y3);
    ((float2*)(fe + (size_t)i * E_))[tt] = r;
  }
}

// K2: energy GEMV (block 124 also computes mean row); last-finishing block does
//     masked softmax + log_aw + argmax + awf + fmaxrow (threadfence+ticket pattern)
__global__ __launch_bounds__(256) void k_energy(float* __restrict__ fe,
                                                const float* __restrict__ a1W,
                                                const float* __restrict__ ebias,
                                                const float* __restrict__ a2W,
                                                const float* __restrict__ a2b,
                                                const int* __restrict__ nfp,
                                                float* __restrict__ energy,
                                                float* __restrict__ awf,
                                                float* __restrict__ fmaxrow,
                                                float* __restrict__ out_logaw,
                                                int* __restrict__ cnt) {
  __shared__ float sfe[4][E_];
  __shared__ float sred[4][256];
  __shared__ float saw[512];
  __shared__ int sticket;
  const int t = threadIdx.x;
  const int i0 = blockIdx.x * 4;
  const int nf = *nfp;

  if (blockIdx.x == 124) {
    float s0 = 0.f, s1 = 0.f, s2 = 0.f, s3 = 0.f;
    int i = 0;
    for (; i + 4 <= nf; i += 4) {
      s0 += fe[(i + 0) * E_ + t]; s1 += fe[(i + 1) * E_ + t];
      s2 += fe[(i + 2) * E_ + t]; s3 += fe[(i + 3) * E_ + t];
    }
    for (; i < nf; ++i) s0 += fe[i * E_ + t];
    float mv = ((s0 + s1) + (s2 + s3)) / (float)nf;
    sfe[3][t] = mv;
    fe[CTX_ * E_ + t] = mv;
    sfe[0][t] = fe[496 * E_ + t];
    sfe[1][t] = fe[497 * E_ + t];
    sfe[2][t] = fe[498 * E_ + t];
  } else {
#pragma unroll
    for (int r = 0; r < 4; ++r) sfe[r][t] = fe[(i0 + r) * E_ + t];
  }
  __syncthreads();
  float c0 = 0.f, c1 = 0.f, c2 = 0.f, c3 = 0.f;
  const float4* s0p = (const float4*)sfe[0];
  const float4* s1p = (const float4*)sfe[1];
  const float4* s2p = (const float4*)sfe[2];
  const float4* s3p = (const float4*)sfe[3];
  for (int j = t; j < MCL_; j += 256) {
    const float4* w4 = (const float4*)(a1W + (size_t)j * (E_ + H_));
    float d0 = 0.f, d1 = 0.f, d2 = 0.f, d3 = 0.f;
#pragma unroll 8
    for (int q = 0; q < E_ / 4; ++q) {
      float4 a = w4[q];
      d0 += dot4(a, s0p[q]);
      d1 += dot4(a, s1p[q]);
      d2 += dot4(a, s2p[q]);
      d3 += dot4(a, s3p[q]);
    }
    float bj = ebias[j], wj = a2W[j];
    c0 = fmaf(wj, tanhf(d0 + bj), c0);
    c1 = fmaf(wj, tanhf(d1 + bj), c1);
    c2 = fmaf(wj, tanhf(d2 + bj), c2);
    c3 = fmaf(wj, tanhf(d3 + bj), c3);
  }
  sred[0][t] = c0; sred[1][t] = c1; sred[2][t] = c2; sred[3][t] = c3;
  __syncthreads();
  for (int s = 128; s; s >>= 1) {
    if (t < s) {
#pragma unroll
      for (int r = 0; r < 4; ++r) sred[r][t] += sred[r][t + s];
    }
    __syncthreads();
  }
  if (t < 4) energy[i0 + t] = sred[t][0] + a2b[0];

  __threadfence();
  if (t == 0) sticket = atomicAdd(cnt, 1);
  __syncthreads();
  if (sticket != 124) return;
  __threadfence();

  // ---- softmax tail (256 threads over 500 energies) ----
  float* red = sred[0];
  int* idx = (int*)sred[1];
  float ev0 = energy[t];
  float ev1 = (t + 256 < MCL_) ? energy[t + 256] : -1e30f;
  red[t] = fmaxf(ev0, ev1); __syncthreads();
  for (int s = 128; s; s >>= 1) { if (t < s) red[t] = fmaxf(red[t], red[t + s]); __syncthreads(); }
  const float mx = red[0]; __syncthreads();

  float p0 = __expf(ev0 - mx);
  float p1 = (t + 256 < MCL_) ? __expf(ev1 - mx) : 0.f;
  red[t] = p0 + p1; __syncthreads();
  for (int s = 128; s; s >>= 1) { if (t < s) red[t] += red[t + s]; __syncthreads(); }
  const float S1 = red[0]; __syncthreads();

  float m0 = ((t < nf) || (t == MCL_ - 1)) ? 1.f : 0.f;
  float m1 = (((t + 256) < nf) || ((t + 256) == MCL_ - 1)) ? 1.f : 0.f;
  float a0 = p0 / S1 * m0 + EPS_;
  float a1 = (t + 256 < MCL_) ? (p1 / S1 * m1 + EPS_) : 0.f;
  red[t] = a0 + a1; __syncthreads();
  for (int s = 128; s; s >>= 1) { if (t < s) red[t] += red[t + s]; __syncthreads(); }
  const float S2 = red[0]; __syncthreads();

  a0 /= S2; a1 /= S2;
  out_logaw[t] = logf(a0);
  if (t + 256 < MCL_) out_logaw[t + 256] = logf(a1);
  saw[t] = a0;
  saw[t + 256] = (t + 256 < MCL_) ? a1 : 0.f;

  float bv; int bi;
  if ((t + 256 < MCL_) && (a1 > a0)) { bv = a1; bi = t + 256; } else { bv = a0; bi = t; }
  red[t] = bv; idx[t] = bi; __syncthreads();
  for (int s = 128; s; s >>= 1) {
    if (t < s) {
      float o = red[t + s]; int oi = idx[t + s];
      if (o > red[t] || (o == red[t] && oi < idx[t])) { red[t] = o; idx[t] = oi; }
    }
    __syncthreads();
  }
  const int fidx = idx[0]; __syncthreads();

  float pa = 0.f, pb = 0.f;
  for (int i2 = 0; i2 < MCL_; i2 += 2) {
    pa = fmaf(saw[i2], fe[i2 * E_ + t], pa);
    pb = fmaf(saw[i2 + 1], fe[(i2 + 1) * E_ + t], pb);
  }
  awf[t] = pa + pb;
  fmaxrow[t] = fe[fidx * E_ + t];
}

// K3: fused gates + GRU: each wave owns one h; 6 dot-512s, lane0 combines
__global__ __launch_bounds__(256) void k_gates_gru(const float* __restrict__ Wih,
                                                   const float* __restrict__ bih,
                                                   const float* __restrict__ Whh,
                                                   const float* __restrict__ bhh,
                                                   const float* __restrict__ wemb,
                                                   const float* __restrict__ fmaxrow,
                                                   const float* __restrict__ h0,
                                                   float* __restrict__ hnew,
                                                   float* __restrict__ out_hidden) {
  const int t = threadIdx.x, lane = t & 63, w = t >> 6;
  const int h = blockIdx.x * 4 + w;
  const float4* xa4 = (const float4*)(wemb + E_);  // word_emb row 1
  const float4* xb4 = (const float4*)fmaxrow;
  const float4* h4  = (const float4*)h0;
  float4 xav = xa4[lane], xbv = xb4[lane];
  float4 hva = h4[lane], hvb = h4[lane + 64];
  const float* rr = Wih + (size_t)h * (2 * E_ + F_);
  const float* rz = Wih + (size_t)(H_ + h) * (2 * E_ + F_);
  const float* rn = Wih + (size_t)(2 * H_ + h) * (2 * E_ + F_);
  float gir = dot4(((const float4*)rr)[lane], xav) + dot4(((const float4*)(rr + E_ + F_))[lane], xbv);
  float giz = dot4(((const float4*)rz)[lane], xav) + dot4(((const float4*)(rz + E_ + F_))[lane], xbv);
  float gin = dot4(((const float4*)rn)[lane], xav) + dot4(((const float4*)(rn + E_ + F_))[lane], xbv);
  const float4* wr = (const float4*)(Whh + (size_t)h * H_);
  const float4* wz = (const float4*)(Whh + (size_t)(H_ + h) * H_);
  const float4* wn = (const float4*)(Whh + (size_t)(2 * H_ + h) * H_);
  float ghr = dot4(wr[lane], hva) + dot4(wr[lane + 64], hvb);
  float ghz = dot4(wz[lane], hva) + dot4(wz[lane + 64], hvb);
  float ghn = dot4(wn[lane], hva) + dot4(wn[lane + 64], hvb);
  gir = wred64(gir); giz = wred64(giz); gin = wred64(gin);
  ghr = wred64(ghr); ghz = wred64(ghz); ghn = wred64(ghn);
  if (lane == 0) {
    float r = 1.f / (1.f + __expf(-(gir + bih[h] + ghr + bhh[h])));
    float z = 1.f / (1.f + __expf(-(giz + bih[H_ + h] + ghz + bhh[H_ + h])));
    float n = tanhf(gin + bih[2 * H_ + h] + r * (ghn + bhh[2 * H_ + h]));
    float hv = (1.f - z) * n + z * h0[h];
    hnew[h] = hv;
    out_hidden[h] = hv;
  }
}

// K4: act = relu([h_new|awf] . out1_W^T + out1_b)
__global__ __launch_bounds__(256) void k_out1(const float* __restrict__ o1W,
                                              const float* __restrict__ o1b,
                                              const float* __restrict__ hnew,
                                              const float* __restrict__ awf,
                                              float* __restrict__ act) {
  __shared__ float cat[H_ + E_];
  const int t = threadIdx.x;
#pragma unroll
  for (int idx = t; idx < H_; idx += 256) cat[idx] = hnew[idx];
  cat[H_ + t] = awf[t];
  __syncthreads();
  const int lane = t & 63, sub = lane & 15, grp = lane >> 4;
  const int gw = blockIdx.x * 4 + (t >> 6);
  const float4* c4 = (const float4*)cat;
  const int r = gw * 4 + grp;
  const float4* w4 = (const float4*)(o1W + (size_t)r * (H_ + E_));
  float acc = 0.f;
#pragma unroll
  for (int q = 0; q < 12; ++q) acc += dot4(w4[sub + q * 16], c4[sub + q * 16]);
  acc = qred16(acc);
  if (sub == 0) act[r] = fmaxf(acc + o1b[r], 0.f);
}

// K5: vocab GEMV, 8 rows/wave/iter (two 4-row groups, 16 NT loads in flight)
__global__ __launch_bounds__(256) void k_vocab(const float* __restrict__ o2W,
                                               const float* __restrict__ o2b,
                                               const float* __restrict__ act,
                                               float* __restrict__ logits,
                                               float* __restrict__ bsum) {
  __shared__ float swsum[4];
  const int t = threadIdx.x;
  const int lane = t & 63, sub = lane & 15, grp = lane >> 4, w = t >> 6;
  const int gw = blockIdx.x * 4 + w;
  const int nW = 1024 * 4;
  const f4v* a4 = (const f4v*)act;
  f4v ar[8];
#pragma unroll
  for (int q = 0; q < 8; ++q) ar[q] = a4[sub + q * 16];
  float sumexp = 0.f;
  for (int v0 = gw * 8; v0 < V_; v0 += nW * 8) {
    const int vA = v0 + grp;
    const int vB = v0 + 4 + grp;
    float accA = 0.f, accB = 0.f;
    if (vB < V_) {
      const f4v* wa = (const f4v*)(o2W + (size_t)vA * H_);
      const f4v* wb = (const f4v*)(o2W + (size_t)vB * H_);
      f4v la[8], lb[8];
#pragma unroll
      for (int q = 0; q < 8; ++q) la[q] = __builtin_nontemporal_load(&wa[sub + q * 16]);
#pragma unroll
      for (int q = 0; q < 8; ++q) lb[q] = __builtin_nontemporal_load(&wb[sub + q * 16]);
#pragma unroll
      for (int q = 0; q < 8; ++q) { accA += dot4v(la[q], ar[q]); accB += dot4v(lb[q], ar[q]); }
    } else if (vA < V_) {
      const f4v* wa = (const f4v*)(o2W + (size_t)vA * H_);
      f4v la[8];
#pragma unroll
      for (int q = 0; q < 8; ++q) la[q] = __builtin_nontemporal_load(&wa[sub + q * 16]);
#pragma unroll
      for (int q = 0; q < 8; ++q) accA += dot4v(la[q], ar[q]);
    }
    accA = qred16(accA);
    accB = qred16(accB);
    if (sub == 0) {
      if (vA < V_) { float lg = accA + o2b[vA]; logits[vA] = lg; sumexp += __expf(lg); }
      if (vB < V_) { float lg = accB + o2b[vB]; logits[vB] = lg; sumexp += __expf(lg); }
    }
  }
  sumexp = wred64(sumexp);
  if (lane == 0) swsum[w] = sumexp;
  __syncthreads();
  if (t == 0) bsum[blockIdx.x] = swsum[0] + swsum[1] + swsum[2] + swsum[3];
}

// K6: redundant logZ reduce per block + y = logits - logZ
__global__ __launch_bounds__(256) void k_final(const float* __restrict__ logits,
                                               const float* __restrict__ bsum,
                                               float* __restrict__ y) {
  __shared__ float sr[256];
  const int t = threadIdx.x;
  float s = bsum[t] + bsum[t + 256] + bsum[t + 512] + bsum[t + 768];
  sr[t] = s; __syncthreads();
  for (int o = 128; o; o >>= 1) { if (t < o) sr[t] += sr[t + o]; __syncthreads(); }
  const float lz = logf(sr[0]);
  const int i = blockIdx.x * 256 + t;
  float4 l = ((const float4*)logits)[i];
  ((float4*)y)[i] = make_float4(l.x - lz, l.y - lz, l.z - lz, l.w - lz);
}

extern "C" void kernel_launch(void* const* d_in, const int* in_sizes, int n_in,
                              void* d_out, int out_size, void* d_ws, size_t ws_size,
                              hipStream_t stream) {
  const int*   ctx  = (const int*)d_in[0];
  const float* wemb = (const float*)d_in[1];
  const float* a1W  = (const float*)d_in[2];
  const float* a1b  = (const float*)d_in[3];
  const float* a2W  = (const float*)d_in[4];
  const float* a2b  = (const float*)d_in[5];
  const float* Wih  = (const float*)d_in[6];
  const float* Whh  = (const float*)d_in[7];
  const float* bih  = (const float*)d_in[8];
  const float* bhh  = (const float*)d_in[9];
  const float* o1W  = (const float*)d_in[10];
  const float* o1b  = (const float*)d_in[11];
  const float* o2W  = (const float*)d_in[12];
  const float* o2b  = (const float*)d_in[13];
  const float* h0   = (const float*)d_in[14];
  const int*   nfp  = (const int*)d_in[15];
  float* ws = (float*)d_ws;
  float* y  = (float*)d_out;
  int* cnt = (int*)(ws + WS_CNT);

  k_encode<<<258, 256, 0, stream>>>(ctx, wemb, ws + WS_FE, a1W, a1b, h0,
                                    ws + WS_EBIAS, cnt);
  k_energy<<<125, 256, 0, stream>>>(ws + WS_FE, a1W, ws + WS_EBIAS, a2W, a2b, nfp,
                                    ws + WS_ENERGY, ws + WS_AWF, ws + WS_FMAX,
                                    y + V_, cnt);
  k_gates_gru<<<128, 256, 0, stream>>>(Wih, bih, Whh, bhh, wemb, ws + WS_FMAX, h0,
                                       ws + WS_HNEW, y + V_ + MCL_);
  k_out1<<<32, 256, 0, stream>>>(o1W, o1b, ws + WS_HNEW, ws + WS_AWF, ws + WS_ACT);
  k_vocab<<<1024, 256, 0, stream>>>(o2W, o2b, ws + WS_ACT, ws + WS_LOGITS, ws + WS_BSUM);
  k_final<<<V_ / 1024, 256, 0, stream>>>(ws + WS_LOGITS, ws + WS_BSUM, y);
}